// Round 1
// baseline (84.025 us; speedup 1.0000x reference)
//
#include <hip/hip_runtime.h>

#define S_LEN 2048
#define D_DIM 256
#define WIN 33
#define HALF 16
#define TROWS 16
#define SPAN 48         // cols 48..63 of the 64-wide frame are always out-of-band
#define SC_STRIDE 68    // f32
#define PT_STRIDE 72    // shorts; row pitch 144 B -> b128 frag reads 16B-aligned

typedef __attribute__((ext_vector_type(8))) short short8_t;
typedef __attribute__((ext_vector_type(4))) float f32x4;

// two f32 -> packed bf16x2, round-half-away: 2 adds + 1 v_perm
__device__ inline unsigned pack2_bf16(float lo, float hi) {
    unsigned a = __float_as_uint(lo) + 0x8000u;
    unsigned b = __float_as_uint(hi) + 0x8000u;
    return __builtin_amdgcn_perm(b, a, 0x07060302);
}
__device__ inline short8_t pack_bf16x8(float4 x, float4 y) {
    union { unsigned u[4]; short8_t s; } r;
    r.u[0] = pack2_bf16(x.x, x.y); r.u[1] = pack2_bf16(x.z, x.w);
    r.u[2] = pack2_bf16(y.x, y.y); r.u[3] = pack2_bf16(y.z, y.w);
    return r.s;
}

// LDS-only barrier: drains ds ops (lgkmcnt) but leaves register-destined
// global loads (vmcnt) in flight across the barrier. __syncthreads() would
// drain vmcnt(0) and put the V-load latency on the critical path.
__device__ inline void lds_barrier() {
    asm volatile("s_waitcnt lgkmcnt(0)\n\ts_barrier" ::: "memory");
}

// 512 blocks x 512 threads (8 waves). __launch_bounds__(512,4): cap VGPR at
// 128 so 2 blocks/CU are GUARANTEED co-resident — the phase-interleave that
// hides barrier gaps depends on it. Tile = 16 query rows, span 48.
// Waves 0..2: one 16x16 QK tile each. All waves: issue V-operand loads
// pre-barrier (registers, vmcnt stays in flight across softmax); pack to
// bf16 fragments post-barrier-2 where they are consumed.
// Interior tiles (504/512): clamp-free V addressing, base + imm offsets.
__global__ __launch_bounds__(512, 4) void local_attn_v8(
    const float* __restrict__ q,
    const float* __restrict__ k,
    const float* __restrict__ v,
    const int*   __restrict__ mask,
    float* __restrict__ out_v,   // [B*S*D]
    float* __restrict__ out_p)   // [B*S*WIN]
{
    __shared__ __align__(16) float          Sc[TROWS * SC_STRIDE];  // 4.35 KB
    __shared__ __align__(16) unsigned short Pt[TROWS * PT_STRIDE];  // 2.25 KB
    __shared__ int wm[SPAN];

    const int t    = threadIdx.x;
    const int lane = t & 63;
    const int w    = t >> 6;          // wave 0..7
    const int l15  = lane & 15;
    const int q4   = lane >> 4;

    const int bid  = blockIdx.x;                      // 0..511
    const int tile = ((bid & 7) << 6) | (bid >> 3);   // XCD-contiguous stripes
    const int b    = tile >> 7;                       // 128 tiles per batch
    const int ts   = tile & 127;
    const int s0   = ts << 4;                         // first query row
    const bool interior = (ts >= 1) && (ts <= 126);   // frame rows all in [0,S)

    const float* qb = q + ((size_t)b * S_LEN + s0) * D_DIM;
    const float* kb = k + (size_t)b * S_LEN * D_DIM;
    const float* vb = v + (size_t)b * S_LEN * D_DIM;

    if (t < SPAN) {
        const int idx = s0 - HALF + t;
        wm[t] = (idx >= 0 && idx < S_LEN) ? (mask[b * S_LEN + idx] != 0) : 0;
    }

    // V-operand staging registers: B-frag[nt][ks][j] = V[g][d],
    // g = ks*32 + q4*8 + j, d = 32w + nt*16 + l15. ks=1 only for q4<2
    // (g<48); rows 48..63 of the frame have P==0 -> zero fragment.
    float vr[2][2][8];
    const bool act1 = (q4 < 2);

    if (interior) {
        // ---- Phase A1 (waves 0..2): QK 16x16 tile, col-tile w, no clamps ----
        if (w < 3) {
            const int c = 16 * w + l15;                 // span col 0..47
            const float* kr = kb + (size_t)(s0 - HALF + c) * D_DIM;
            const float* qr = qb + (size_t)l15 * D_DIM;
            f32x4 acc = (f32x4){0.f, 0.f, 0.f, 0.f};
#pragma unroll
            for (int ks = 0; ks < 8; ++ks) {
                const float* pq = qr + ks * 32 + q4 * 8;
                const float* pk = kr + ks * 32 + q4 * 8;
                const short8_t aq = pack_bf16x8(*(const float4*)pq, *(const float4*)(pq + 4));
                const short8_t bk = pack_bf16x8(*(const float4*)pk, *(const float4*)(pk + 4));
                acc = __builtin_amdgcn_mfma_f32_16x16x32_bf16(aq, bk, acc, 0, 0, 0);
            }
#pragma unroll
            for (int r = 0; r < 4; ++r)
                Sc[(q4 * 4 + r) * SC_STRIDE + c] = acc[r];
        }
        // ---- Phase A2 (all waves): issue V loads. One base/lane, j*1024 B
        // immediate offsets (compiler splits into two bases for j>=4). ----
        const float* pv = vb + (size_t)(s0 - HALF + q4 * 8) * D_DIM + 32 * w + l15;
#pragma unroll
        for (int nt = 0; nt < 2; ++nt) {
            const float* p0 = pv + nt * 16;
#pragma unroll
            for (int j = 0; j < 8; ++j)
                vr[nt][0][j] = p0[(size_t)j * D_DIM];
            if (act1) {
                const float* p1 = p0 + (size_t)32 * D_DIM;
#pragma unroll
                for (int j = 0; j < 8; ++j)
                    vr[nt][1][j] = p1[(size_t)j * D_DIM];
            }
        }
    } else {
        // ---- Boundary tiles (8 of 512): generic clamped path ----
        if (w < 3) {
            const int c    = 16 * w + l15;
            const int kidx = min(max(s0 - HALF + c, 0), S_LEN - 1);
            const float* kr = kb + (size_t)kidx * D_DIM;
            const float* qr = qb + (size_t)l15 * D_DIM;
            f32x4 acc = (f32x4){0.f, 0.f, 0.f, 0.f};
#pragma unroll
            for (int ks = 0; ks < 8; ++ks) {
                const float* pq = qr + ks * 32 + q4 * 8;
                const float* pk = kr + ks * 32 + q4 * 8;
                const short8_t aq = pack_bf16x8(*(const float4*)pq, *(const float4*)(pq + 4));
                const short8_t bk = pack_bf16x8(*(const float4*)pk, *(const float4*)(pk + 4));
                acc = __builtin_amdgcn_mfma_f32_16x16x32_bf16(aq, bk, acc, 0, 0, 0);
            }
#pragma unroll
            for (int r = 0; r < 4; ++r)
                Sc[(q4 * 4 + r) * SC_STRIDE + c] = acc[r];
        }
#pragma unroll
        for (int nt = 0; nt < 2; ++nt) {
            const int d = 32 * w + nt * 16 + l15;
#pragma unroll
            for (int j = 0; j < 8; ++j) {
                const int g0   = q4 * 8 + j;
                const int idx0 = min(max(s0 - HALF + g0, 0), S_LEN - 1);
                vr[nt][0][j] = vb[(size_t)idx0 * D_DIM + d];
            }
            if (act1) {
#pragma unroll
                for (int j = 0; j < 8; ++j) {
                    const int g1   = 32 + q4 * 8 + j;   // < 48 when q4 < 2
                    const int idx1 = min(max(s0 - HALF + g1, 0), S_LEN - 1);
                    vr[nt][1][j] = vb[(size_t)idx1 * D_DIM + d];
                }
            }
        }
    }

    lds_barrier();   // Sc/wm visible; V loads still in flight (vmcnt)

    // ---- Phase B: softmax, row = t>>5 (0..15), thread covers cols 2e, 2e+1 ----
    {
        const int row = t >> 5;
        const int e   = t & 31;
        float vs[2];
#pragma unroll
        for (int kq = 0; kq < 2; ++kq) {
            const int c = 2 * e + kq;                   // frame col 0..63
            const int j = c - row;
            const bool inb = (j >= 0) && (j < WIN) && (c < SPAN);
            vs[kq] = inb ? (wm[c < SPAN ? c : 0] ? Sc[row * SC_STRIDE + (c < SPAN ? c : 0)] * 0.0625f
                                                 : -1e10f)
                         : -1e30f;
        }
        float m = fmaxf(vs[0], vs[1]);
        m = fmaxf(m, __shfl_xor(m, 1, 64));
        m = fmaxf(m, __shfl_xor(m, 2, 64));
        m = fmaxf(m, __shfl_xor(m, 4, 64));
        m = fmaxf(m, __shfl_xor(m, 8, 64));
        m = fmaxf(m, __shfl_xor(m, 16, 64));
        float s = 0.f;
#pragma unroll
        for (int kq = 0; kq < 2; ++kq) { vs[kq] = __expf(vs[kq] - m); s += vs[kq]; }
        s += __shfl_xor(s, 1, 64);
        s += __shfl_xor(s, 2, 64);
        s += __shfl_xor(s, 4, 64);
        s += __shfl_xor(s, 8, 64);
        s += __shfl_xor(s, 16, 64);
        const float rinv = 1.0f / s;

        float p0 = vs[0] * rinv, p1 = vs[1] * rinv;     // exact 0 out-of-band
        *(unsigned*)&Pt[row * PT_STRIDE + 2 * e] = pack2_bf16(p0, p1);
        float* prow = out_p + ((size_t)(b * S_LEN + s0 + row)) * WIN;
        const int j0 = 2 * e - row;
        if (j0 >= 0 && j0 < WIN)         prow[j0]     = p0;
        if (j0 + 1 >= 0 && j0 + 1 < WIN) prow[j0 + 1] = p1;
    }

    lds_barrier();   // Pt visible

    // ---- Phase C: pack V frags (vmcnt waits land here), then PV ----
    {
        const short8_t zfrag = {0, 0, 0, 0, 0, 0, 0, 0};
        short8_t bv[2][2];
#pragma unroll
        for (int nt = 0; nt < 2; ++nt) {
            float4 x, y;
            x.x = vr[nt][0][0]; x.y = vr[nt][0][1]; x.z = vr[nt][0][2]; x.w = vr[nt][0][3];
            y.x = vr[nt][0][4]; y.y = vr[nt][0][5]; y.z = vr[nt][0][6]; y.w = vr[nt][0][7];
            bv[nt][0] = pack_bf16x8(x, y);
            if (act1) {
                x.x = vr[nt][1][0]; x.y = vr[nt][1][1]; x.z = vr[nt][1][2]; x.w = vr[nt][1][3];
                y.x = vr[nt][1][4]; y.y = vr[nt][1][5]; y.z = vr[nt][1][6]; y.w = vr[nt][1][7];
                bv[nt][1] = pack_bf16x8(x, y);
            } else {
                bv[nt][1] = zfrag;
            }
        }

        const short8_t ap0 = *(const short8_t*)&Pt[l15 * PT_STRIDE + q4 * 8];
        const short8_t ap1 = *(const short8_t*)&Pt[l15 * PT_STRIDE + 32 + q4 * 8];
        float* ob = out_v + ((size_t)b * S_LEN + s0) * D_DIM;
#pragma unroll
        for (int nt = 0; nt < 2; ++nt) {
            f32x4 acc = (f32x4){0.f, 0.f, 0.f, 0.f};
            acc = __builtin_amdgcn_mfma_f32_16x16x32_bf16(ap0, bv[nt][0], acc, 0, 0, 0);
            acc = __builtin_amdgcn_mfma_f32_16x16x32_bf16(ap1, bv[nt][1], acc, 0, 0, 0);
            const int d = 32 * w + nt * 16 + l15;
#pragma unroll
            for (int r = 0; r < 4; ++r)
                ob[(size_t)(q4 * 4 + r) * D_DIM + d] = acc[r];
        }
    }
}

extern "C" void kernel_launch(void* const* d_in, const int* in_sizes, int n_in,
                              void* d_out, int out_size, void* d_ws, size_t ws_size,
                              hipStream_t stream) {
    const float* q    = (const float*)d_in[0];
    const float* k    = (const float*)d_in[1];
    const float* v    = (const float*)d_in[2];
    const int*   mask = (const int*)d_in[3];

    const int B = 4;
    float* out_v = (float*)d_out;
    float* out_p = (float*)d_out + (size_t)B * S_LEN * D_DIM;

    const int blocks = B * (S_LEN / TROWS);   // 512 blocks x 512 threads
    local_attn_v8<<<blocks, 512, 0, stream>>>(q, k, v, mask, out_v, out_p);
}

// Round 2
// 83.297 us; speedup vs baseline: 1.0087x; 1.0087x over previous
//
#include <hip/hip_runtime.h>

#define S_LEN 2048
#define D_DIM 256
#define WIN 33
#define HALF 16
#define TROWS 16
#define SPAN 48         // cols 48..63 of the 64-wide frame are always out-of-band
#define SC_STRIDE 68    // f32
#define PT_STRIDE 72    // shorts; row pitch 144 B -> b128 frag reads 16B-aligned

typedef __attribute__((ext_vector_type(8))) short short8_t;
typedef __attribute__((ext_vector_type(4))) float f32x4;

// two f32 -> packed bf16x2, round-half-away: 2 adds + 1 v_perm
__device__ inline unsigned pack2_bf16(float lo, float hi) {
    unsigned a = __float_as_uint(lo) + 0x8000u;
    unsigned b = __float_as_uint(hi) + 0x8000u;
    return __builtin_amdgcn_perm(b, a, 0x07060302);
}
__device__ inline short8_t pack_bf16x8(float4 x, float4 y) {
    union { unsigned u[4]; short8_t s; } r;
    r.u[0] = pack2_bf16(x.x, x.y); r.u[1] = pack2_bf16(x.z, x.w);
    r.u[2] = pack2_bf16(y.x, y.y); r.u[3] = pack2_bf16(y.z, y.w);
    return r.s;
}

// LDS-only barrier: drains ds ops (lgkmcnt) but leaves register-destined
// global loads (vmcnt) in flight across the barrier.
__device__ inline void lds_barrier() {
    asm volatile("s_waitcnt lgkmcnt(0)\n\ts_barrier" ::: "memory");
}

// v9: QK split-K across 6 waves. Wave w in 0..5 handles col-tile (w>>1),
// K-half (w&1): 4 ks-steps (16 loads, 4 MFMAs) instead of 8 — halves the
// pre-barrier-1 critical chain that v8's null result implicated. Partial
// sums land in Sc[0]/Sc[1]; softmax adds them (1 extra LDS read + fadd).
// Everything else (V preload in regs across barriers, deferred bf16 pack,
// 2-barrier softmax, PV 2-MFMA/wave) unchanged from v8.
__global__ __launch_bounds__(512, 4) void local_attn_v9(
    const float* __restrict__ q,
    const float* __restrict__ k,
    const float* __restrict__ v,
    const int*   __restrict__ mask,
    float* __restrict__ out_v,   // [B*S*D]
    float* __restrict__ out_p)   // [B*S*WIN]
{
    __shared__ __align__(16) float          Sc[2][TROWS * SC_STRIDE];  // 8.7 KB
    __shared__ __align__(16) unsigned short Pt[TROWS * PT_STRIDE];     // 2.25 KB
    __shared__ int wm[SPAN];

    const int t    = threadIdx.x;
    const int lane = t & 63;
    const int w    = t >> 6;          // wave 0..7
    const int l15  = lane & 15;
    const int q4   = lane >> 4;

    const int bid  = blockIdx.x;                      // 0..511
    const int tile = ((bid & 7) << 6) | (bid >> 3);   // XCD-contiguous stripes
    const int b    = tile >> 7;                       // 128 tiles per batch
    const int ts   = tile & 127;
    const int s0   = ts << 4;                         // first query row
    const bool interior = (ts >= 1) && (ts <= 126);   // frame rows all in [0,S)

    const float* qb = q + ((size_t)b * S_LEN + s0) * D_DIM;
    const float* kb = k + (size_t)b * S_LEN * D_DIM;
    const float* vb = v + (size_t)b * S_LEN * D_DIM;

    if (t < SPAN) {
        const int idx = s0 - HALF + t;
        wm[t] = (idx >= 0 && idx < S_LEN) ? (mask[b * S_LEN + idx] != 0) : 0;
    }

    // V-operand staging registers: B-frag[nt][ks][j] = V[g][d],
    // g = ks*32 + q4*8 + j, d = 32w + nt*16 + l15. ks=1 only for q4<2
    // (g<48); rows 48..63 of the frame have P==0 -> zero fragment.
    float vr[2][2][8];
    const bool act1 = (q4 < 2);

    if (interior) {
        // ---- Phase A1 (waves 0..5): QK 16x16 tile (w>>1), K-half (w&1) ----
        if (w < 6) {
            const int tl = w >> 1;                      // col-tile 0..2
            const int h  = w & 1;                       // K-half
            const int c  = 16 * tl + l15;               // span col 0..47
            const float* kr = kb + (size_t)(s0 - HALF + c) * D_DIM;
            const float* qr = qb + (size_t)l15 * D_DIM;
            f32x4 acc = (f32x4){0.f, 0.f, 0.f, 0.f};
#pragma unroll
            for (int i = 0; i < 4; ++i) {
                const int ks = 4 * h + i;
                const float* pq = qr + ks * 32 + q4 * 8;
                const float* pk = kr + ks * 32 + q4 * 8;
                const short8_t aq = pack_bf16x8(*(const float4*)pq, *(const float4*)(pq + 4));
                const short8_t bk = pack_bf16x8(*(const float4*)pk, *(const float4*)(pk + 4));
                acc = __builtin_amdgcn_mfma_f32_16x16x32_bf16(aq, bk, acc, 0, 0, 0);
            }
#pragma unroll
            for (int r = 0; r < 4; ++r)
                Sc[h][(q4 * 4 + r) * SC_STRIDE + c] = acc[r];
        }
        // ---- Phase A2 (all waves): issue V loads (clamp-free) ----
        const float* pv = vb + (size_t)(s0 - HALF + q4 * 8) * D_DIM + 32 * w + l15;
#pragma unroll
        for (int nt = 0; nt < 2; ++nt) {
            const float* p0 = pv + nt * 16;
#pragma unroll
            for (int j = 0; j < 8; ++j)
                vr[nt][0][j] = p0[(size_t)j * D_DIM];
            if (act1) {
                const float* p1 = p0 + (size_t)32 * D_DIM;
#pragma unroll
                for (int j = 0; j < 8; ++j)
                    vr[nt][1][j] = p1[(size_t)j * D_DIM];
            }
        }
    } else {
        // ---- Boundary tiles (8 of 512): generic clamped path ----
        if (w < 6) {
            const int tl = w >> 1;
            const int h  = w & 1;
            const int c    = 16 * tl + l15;
            const int kidx = min(max(s0 - HALF + c, 0), S_LEN - 1);
            const float* kr = kb + (size_t)kidx * D_DIM;
            const float* qr = qb + (size_t)l15 * D_DIM;
            f32x4 acc = (f32x4){0.f, 0.f, 0.f, 0.f};
#pragma unroll
            for (int i = 0; i < 4; ++i) {
                const int ks = 4 * h + i;
                const float* pq = qr + ks * 32 + q4 * 8;
                const float* pk = kr + ks * 32 + q4 * 8;
                const short8_t aq = pack_bf16x8(*(const float4*)pq, *(const float4*)(pq + 4));
                const short8_t bk = pack_bf16x8(*(const float4*)pk, *(const float4*)(pk + 4));
                acc = __builtin_amdgcn_mfma_f32_16x16x32_bf16(aq, bk, acc, 0, 0, 0);
            }
#pragma unroll
            for (int r = 0; r < 4; ++r)
                Sc[h][(q4 * 4 + r) * SC_STRIDE + c] = acc[r];
        }
#pragma unroll
        for (int nt = 0; nt < 2; ++nt) {
            const int d = 32 * w + nt * 16 + l15;
#pragma unroll
            for (int j = 0; j < 8; ++j) {
                const int g0   = q4 * 8 + j;
                const int idx0 = min(max(s0 - HALF + g0, 0), S_LEN - 1);
                vr[nt][0][j] = vb[(size_t)idx0 * D_DIM + d];
            }
            if (act1) {
#pragma unroll
                for (int j = 0; j < 8; ++j) {
                    const int g1   = 32 + q4 * 8 + j;   // < 48 when q4 < 2
                    const int idx1 = min(max(s0 - HALF + g1, 0), S_LEN - 1);
                    vr[nt][1][j] = vb[(size_t)idx1 * D_DIM + d];
                }
            }
        }
    }

    lds_barrier();   // Sc/wm visible; V loads still in flight (vmcnt)

    // ---- Phase B: softmax, row = t>>5 (0..15), thread covers cols 2e, 2e+1 ----
    {
        const int row = t >> 5;
        const int e   = t & 31;
        float vs[2];
#pragma unroll
        for (int kq = 0; kq < 2; ++kq) {
            const int c  = 2 * e + kq;                  // frame col 0..63
            const int j  = c - row;
            const int cc = (c < SPAN) ? c : 0;
            const bool inb = (j >= 0) && (j < WIN) && (c < SPAN);
            const float sv = (Sc[0][row * SC_STRIDE + cc] + Sc[1][row * SC_STRIDE + cc]) * 0.0625f;
            vs[kq] = inb ? (wm[cc] ? sv : -1e10f) : -1e30f;
        }
        float m = fmaxf(vs[0], vs[1]);
        m = fmaxf(m, __shfl_xor(m, 1, 64));
        m = fmaxf(m, __shfl_xor(m, 2, 64));
        m = fmaxf(m, __shfl_xor(m, 4, 64));
        m = fmaxf(m, __shfl_xor(m, 8, 64));
        m = fmaxf(m, __shfl_xor(m, 16, 64));
        float s = 0.f;
#pragma unroll
        for (int kq = 0; kq < 2; ++kq) { vs[kq] = __expf(vs[kq] - m); s += vs[kq]; }
        s += __shfl_xor(s, 1, 64);
        s += __shfl_xor(s, 2, 64);
        s += __shfl_xor(s, 4, 64);
        s += __shfl_xor(s, 8, 64);
        s += __shfl_xor(s, 16, 64);
        const float rinv = 1.0f / s;

        float p0 = vs[0] * rinv, p1 = vs[1] * rinv;     // exact 0 out-of-band
        *(unsigned*)&Pt[row * PT_STRIDE + 2 * e] = pack2_bf16(p0, p1);
        float* prow = out_p + ((size_t)(b * S_LEN + s0 + row)) * WIN;
        const int j0 = 2 * e - row;
        if (j0 >= 0 && j0 < WIN)         prow[j0]     = p0;
        if (j0 + 1 >= 0 && j0 + 1 < WIN) prow[j0 + 1] = p1;
    }

    lds_barrier();   // Pt visible

    // ---- Phase C: pack V frags (vmcnt waits land here), then PV ----
    {
        const short8_t zfrag = {0, 0, 0, 0, 0, 0, 0, 0};
        short8_t bv[2][2];
#pragma unroll
        for (int nt = 0; nt < 2; ++nt) {
            float4 x, y;
            x.x = vr[nt][0][0]; x.y = vr[nt][0][1]; x.z = vr[nt][0][2]; x.w = vr[nt][0][3];
            y.x = vr[nt][0][4]; y.y = vr[nt][0][5]; y.z = vr[nt][0][6]; y.w = vr[nt][0][7];
            bv[nt][0] = pack_bf16x8(x, y);
            if (act1) {
                x.x = vr[nt][1][0]; x.y = vr[nt][1][1]; x.z = vr[nt][1][2]; x.w = vr[nt][1][3];
                y.x = vr[nt][1][4]; y.y = vr[nt][1][5]; y.z = vr[nt][1][6]; y.w = vr[nt][1][7];
                bv[nt][1] = pack_bf16x8(x, y);
            } else {
                bv[nt][1] = zfrag;
            }
        }

        const short8_t ap0 = *(const short8_t*)&Pt[l15 * PT_STRIDE + q4 * 8];
        const short8_t ap1 = *(const short8_t*)&Pt[l15 * PT_STRIDE + 32 + q4 * 8];
        float* ob = out_v + ((size_t)b * S_LEN + s0) * D_DIM;
#pragma unroll
        for (int nt = 0; nt < 2; ++nt) {
            f32x4 acc = (f32x4){0.f, 0.f, 0.f, 0.f};
            acc = __builtin_amdgcn_mfma_f32_16x16x32_bf16(ap0, bv[nt][0], acc, 0, 0, 0);
            acc = __builtin_amdgcn_mfma_f32_16x16x32_bf16(ap1, bv[nt][1], acc, 0, 0, 0);
            const int d = 32 * w + nt * 16 + l15;
#pragma unroll
            for (int r = 0; r < 4; ++r)
                ob[(size_t)(q4 * 4 + r) * D_DIM + d] = acc[r];
        }
    }
}

extern "C" void kernel_launch(void* const* d_in, const int* in_sizes, int n_in,
                              void* d_out, int out_size, void* d_ws, size_t ws_size,
                              hipStream_t stream) {
    const float* q    = (const float*)d_in[0];
    const float* k    = (const float*)d_in[1];
    const float* v    = (const float*)d_in[2];
    const int*   mask = (const int*)d_in[3];

    const int B = 4;
    float* out_v = (float*)d_out;
    float* out_p = (float*)d_out + (size_t)B * S_LEN * D_DIM;

    const int blocks = B * (S_LEN / TROWS);   // 512 blocks x 512 threads
    local_attn_v9<<<blocks, 512, 0, stream>>>(q, k, v, mask, out_v, out_p);
}